// Round 1
// baseline (303.981 us; speedup 1.0000x reference)
//
#include <hip/hip_runtime.h>

#define B_  4
#define N_  4096
#define H_  16
#define D_  64
#define HD_ 1024
#define BH_ 64
#define S_  4
#define EPS_ 1e-6f

__device__ __forceinline__ float phi(float x) {
    // elu(x)+1 : x>0 -> x+1 ; x<=0 -> exp(x)
    return x > 0.0f ? x + 1.0f : __expf(x);
}

// ---------------------------------------------------------------------------
// Kernel 1a: partial KV[d][m] = sum_n phi(K[n,d]) * V[n,m], and partial Ksum.
// grid (64 bh, 4 split), 256 threads. Each block handles 1024 rows of n.
// ---------------------------------------------------------------------------
__global__ __launch_bounds__(256) void k_kvpart(const float* __restrict__ K,
                                                const float* __restrict__ V,
                                                float* __restrict__ kvpart,
                                                float* __restrict__ kspart) {
    const int bh = blockIdx.x;          // 0..63
    const int s  = blockIdx.y;          // 0..3
    const int b  = bh >> 4;
    const int h  = bh & 15;
    const int t  = threadIdx.x;

    __shared__ float Ks[64][68];
    __shared__ float Vs[64][68];

    float acc[4][4] = {{0.f}};
    float ksum[4]   = {0.f, 0.f, 0.f, 0.f};
    const int dbase = (t >> 4) * 4;
    const int mbase = (t & 15) * 4;

    const float4* Kf4 = (const float4*)K;
    const float4* Vf4 = (const float4*)V;

    for (int chunk = 0; chunk < (N_ / S_) / 64; ++chunk) {
        const int n0 = s * (N_ / S_) + chunk * 64;
        __syncthreads();   // protect LDS from previous iteration's readers
#pragma unroll
        for (int rep = 0; rep < 4; ++rep) {
            int idx = t + rep * 256;            // 0..1023 (float4 index in tile)
            int row = idx >> 4, c4 = idx & 15;
            size_t g = (size_t)(b * N_ + n0 + row) * 256 + h * 16 + c4;
            float4 kv = Kf4[g];
            float4 vv = Vf4[g];
            Ks[row][c4 * 4 + 0] = phi(kv.x);
            Ks[row][c4 * 4 + 1] = phi(kv.y);
            Ks[row][c4 * 4 + 2] = phi(kv.z);
            Ks[row][c4 * 4 + 3] = phi(kv.w);
            *(float4*)&Vs[row][c4 * 4] = vv;
        }
        __syncthreads();
#pragma unroll 8
        for (int n = 0; n < 64; ++n) {
            float4 kd = *(const float4*)&Ks[n][dbase];
            float4 vm = *(const float4*)&Vs[n][mbase];
            float kda[4] = {kd.x, kd.y, kd.z, kd.w};
            float vma[4] = {vm.x, vm.y, vm.z, vm.w};
#pragma unroll
            for (int i = 0; i < 4; ++i) {
#pragma unroll
                for (int j = 0; j < 4; ++j) acc[i][j] += kda[i] * vma[j];
                ksum[i] += kda[i];
            }
        }
    }

    float4* kvp4 = (float4*)kvpart;
    const size_t base = (size_t)(bh * S_ + s) * 4096;
#pragma unroll
    for (int i = 0; i < 4; ++i) {
        float4 o = make_float4(acc[i][0], acc[i][1], acc[i][2], acc[i][3]);
        kvp4[(base + (size_t)(dbase + i) * 64 + mbase) / 4] = o;
    }
    if ((t & 15) == 0) {
#pragma unroll
        for (int i = 0; i < 4; ++i)
            kspart[(size_t)(bh * S_ + s) * 64 + dbase + i] = ksum[i];
    }
}

// ---------------------------------------------------------------------------
// Kernel 1b: reduce partials -> KV, Ksum; M[d][j] = sum_m KV[d][m]*W[j][h*64+m]
// grid 64 blocks (bh), 256 threads. Tiny kernel.
// ---------------------------------------------------------------------------
__global__ __launch_bounds__(256) void k_makeM(const float* __restrict__ kvpart,
                                               const float* __restrict__ kspart,
                                               const float* __restrict__ W,
                                               float* __restrict__ M,
                                               float* __restrict__ Ksum) {
    const int bh = blockIdx.x;
    const int h  = bh & 15;
    const int t  = threadIdx.x;

    __shared__ float KVs[64][68];
    __shared__ float Ws[64][68];    // Ws[j][m]

    const float4* kv4 = (const float4*)kvpart;
    const float4* W4  = (const float4*)W;

    for (int idx = t; idx < 1024; idx += 256) {
        int row = idx >> 4, c4 = idx & 15;
        float4 a = kv4[(size_t)(bh * S_ + 0) * 1024 + idx];
        float4 b1 = kv4[(size_t)(bh * S_ + 1) * 1024 + idx];
        float4 c = kv4[(size_t)(bh * S_ + 2) * 1024 + idx];
        float4 d = kv4[(size_t)(bh * S_ + 3) * 1024 + idx];
        float4 r;
        r.x = a.x + b1.x + c.x + d.x;
        r.y = a.y + b1.y + c.y + d.y;
        r.z = a.z + b1.z + c.z + d.z;
        r.w = a.w + b1.w + c.w + d.w;
        *(float4*)&KVs[row][c4 * 4] = r;
        *(float4*)&Ws[row][c4 * 4] = W4[(size_t)row * 256 + h * 16 + c4];
    }
    if (t < 64) {
        float ks = 0.f;
#pragma unroll
        for (int s = 0; s < S_; ++s) ks += kspart[(size_t)(bh * S_ + s) * 64 + t];
        Ksum[(size_t)bh * 64 + t] = ks;
    }
    __syncthreads();

    const int dbase = (t >> 4) * 4, jbase = (t & 15) * 4;
    float acc[4][4] = {{0.f}};
#pragma unroll 4
    for (int m4 = 0; m4 < 16; ++m4) {
        float4 kvr[4], wr[4];
#pragma unroll
        for (int i = 0; i < 4; ++i) kvr[i] = *(const float4*)&KVs[dbase + i][m4 * 4];
#pragma unroll
        for (int j = 0; j < 4; ++j) wr[j] = *(const float4*)&Ws[jbase + j][m4 * 4];
#pragma unroll
        for (int i = 0; i < 4; ++i)
#pragma unroll
            for (int j = 0; j < 4; ++j)
                acc[i][j] += kvr[i].x * wr[j].x + kvr[i].y * wr[j].y +
                             kvr[i].z * wr[j].z + kvr[i].w * wr[j].w;
    }
    float4* M4 = (float4*)M;
#pragma unroll
    for (int i = 0; i < 4; ++i)
        M4[((size_t)bh * 4096 + (size_t)(dbase + i) * 64 + jbase) / 4] =
            make_float4(acc[i][0], acc[i][1], acc[i][2], acc[i][3]);
}

// ---------------------------------------------------------------------------
// Kernel 2: out[b,n,j] = sum_h z_h(n) * phi(Q_h[n,:]) . M_h[:,j]  + b_out[j]
// grid (64 n-chunks, 4 b), 256 threads; 64 rows of n per block.
// ---------------------------------------------------------------------------
__global__ __launch_bounds__(256) void k_out(const float* __restrict__ Q,
                                             const float* __restrict__ M,
                                             const float* __restrict__ Ksum,
                                             const float* __restrict__ bout,
                                             float* __restrict__ out) {
    const int nc = blockIdx.x;     // 0..63
    const int b  = blockIdx.y;     // 0..3
    const int n0 = nc * 64;
    const int t  = threadIdx.x;

    __shared__ float Ms[64][68];    // Ms[d][j]
    __shared__ float QsT[64][68];   // QsT[d][i]  (transposed)
    __shared__ float zz[64];
    __shared__ float Kss[64];

    const int ibase = (t >> 4) * 4, jbase = (t & 15) * 4;
    float acc[4][4] = {{0.f}};

    const float4* Qf4 = (const float4*)Q;
    const float4* Mf4 = (const float4*)M;

    for (int h = 0; h < H_; ++h) {
        const int bh = b * 16 + h;
        __syncthreads();   // protect LDS (and zz) from previous iteration
        for (int idx = t; idx < 1024; idx += 256) {
            int row = idx >> 4, c4 = idx & 15;
            *(float4*)&Ms[row][c4 * 4] = Mf4[(size_t)bh * 1024 + idx];
            float4 qq = Qf4[(size_t)(b * N_ + n0 + row) * 256 + h * 16 + c4];
            QsT[c4 * 4 + 0][row] = phi(qq.x);
            QsT[c4 * 4 + 1][row] = phi(qq.y);
            QsT[c4 * 4 + 2][row] = phi(qq.z);
            QsT[c4 * 4 + 3][row] = phi(qq.w);
        }
        if (t < 64) Kss[t] = Ksum[(size_t)bh * 64 + t];
        __syncthreads();
        if (t < 64) {
            float sum = 0.f;
#pragma unroll 8
            for (int d = 0; d < 64; ++d) sum += QsT[d][t] * Kss[d];
            zz[t] = 1.0f / (sum + EPS_);
        }
        __syncthreads();

        float sacc[4][4] = {{0.f}};
#pragma unroll 8
        for (int d = 0; d < 64; ++d) {
            float4 qi = *(const float4*)&QsT[d][ibase];
            float4 mj = *(const float4*)&Ms[d][jbase];
            float qa[4] = {qi.x, qi.y, qi.z, qi.w};
            float ma[4] = {mj.x, mj.y, mj.z, mj.w};
#pragma unroll
            for (int i = 0; i < 4; ++i)
#pragma unroll
                for (int j = 0; j < 4; ++j) sacc[i][j] += qa[i] * ma[j];
        }
#pragma unroll
        for (int i = 0; i < 4; ++i) {
            float z = zz[ibase + i];
#pragma unroll
            for (int j = 0; j < 4; ++j) acc[i][j] += z * sacc[i][j];
        }
    }

    float4 bj = *(const float4*)&bout[jbase];
    float4* O4 = (float4*)out;
#pragma unroll
    for (int i = 0; i < 4; ++i) {
        float4 o = make_float4(acc[i][0] + bj.x, acc[i][1] + bj.y,
                               acc[i][2] + bj.z, acc[i][3] + bj.w);
        O4[((size_t)(b * N_ + n0 + ibase + i) * 64 + jbase) / 4] = o;
    }
}

// ---------------------------------------------------------------------------
extern "C" void kernel_launch(void* const* d_in, const int* in_sizes, int n_in,
                              void* d_out, int out_size, void* d_ws, size_t ws_size,
                              hipStream_t stream) {
    const float* q  = (const float*)d_in[0];
    const float* k  = (const float*)d_in[1];
    const float* v  = (const float*)d_in[2];
    const float* W  = (const float*)d_in[3];
    const float* bo = (const float*)d_in[4];
    float* out = (float*)d_out;

    float* ws     = (float*)d_ws;
    float* kvpart = ws;                         // 64*4*4096 = 1048576 floats
    float* kspart = kvpart + (size_t)BH_ * S_ * 4096;   // 64*4*64
    float* M      = kspart + (size_t)BH_ * S_ * 64;     // 64*4096
    float* Ksum   = M + (size_t)BH_ * 4096;             // 64*64

    k_kvpart<<<dim3(BH_, S_), 256, 0, stream>>>(k, v, kvpart, kspart);
    k_makeM<<<BH_, 256, 0, stream>>>(kvpart, kspart, W, M, Ksum);
    k_out<<<dim3(N_ / 64, B_), 256, 0, stream>>>(q, M, Ksum, bo, out);
}

// Round 2
// 263.542 us; speedup vs baseline: 1.1534x; 1.1534x over previous
//
#include <hip/hip_runtime.h>

#define B_  4
#define N_  4096
#define H_  16
#define D_  64
#define BH_ 64
#define EPS_ 1e-6f

__device__ __forceinline__ float phi(float x) {
    // elu(x)+1 : x>0 -> x+1 ; x<=0 -> exp(x)
    return x > 0.0f ? x + 1.0f : __expf(x);
}

// ---------------------------------------------------------------------------
// Kernel 1a: partial KV[d][m] = sum_n phi(K[n,d]) * V[n,m], and partial Ksum.
// grid (64 bh, S splits), 256 threads. Each block handles N_/S rows of n.
// ---------------------------------------------------------------------------
__global__ __launch_bounds__(256) void k_kvpart(const float* __restrict__ K,
                                                const float* __restrict__ V,
                                                float* __restrict__ kvpart,
                                                float* __restrict__ kspart) {
    const int bh = blockIdx.x;          // 0..63
    const int s  = blockIdx.y;          // 0..S-1
    const int S  = gridDim.y;
    const int b  = bh >> 4;
    const int h  = bh & 15;
    const int t  = threadIdx.x;

    __shared__ float Ks[64][68];
    __shared__ float Vs[64][68];

    float acc[4][4] = {{0.f}};
    float ksum[4]   = {0.f, 0.f, 0.f, 0.f};
    const int dbase = (t >> 4) * 4;
    const int mbase = (t & 15) * 4;

    const float4* Kf4 = (const float4*)K;
    const float4* Vf4 = (const float4*)V;

    const int rows   = N_ / S;
    const int chunks = rows / 64;

    for (int chunk = 0; chunk < chunks; ++chunk) {
        const int n0 = s * rows + chunk * 64;
        __syncthreads();   // protect LDS from previous iteration's readers
#pragma unroll
        for (int rep = 0; rep < 4; ++rep) {
            int idx = t + rep * 256;            // 0..1023 (float4 index in tile)
            int row = idx >> 4, c4 = idx & 15;
            size_t g = (size_t)(b * N_ + n0 + row) * 256 + h * 16 + c4;
            float4 kv = Kf4[g];
            float4 vv = Vf4[g];
            Ks[row][c4 * 4 + 0] = phi(kv.x);
            Ks[row][c4 * 4 + 1] = phi(kv.y);
            Ks[row][c4 * 4 + 2] = phi(kv.z);
            Ks[row][c4 * 4 + 3] = phi(kv.w);
            *(float4*)&Vs[row][c4 * 4] = vv;
        }
        __syncthreads();
#pragma unroll 8
        for (int n = 0; n < 64; ++n) {
            float4 kd = *(const float4*)&Ks[n][dbase];
            float4 vm = *(const float4*)&Vs[n][mbase];
            float kda[4] = {kd.x, kd.y, kd.z, kd.w};
            float vma[4] = {vm.x, vm.y, vm.z, vm.w};
#pragma unroll
            for (int i = 0; i < 4; ++i) {
#pragma unroll
                for (int j = 0; j < 4; ++j) acc[i][j] += kda[i] * vma[j];
                ksum[i] += kda[i];
            }
        }
    }

    float4* kvp4 = (float4*)kvpart;
    const size_t base = (size_t)(bh * S + s) * 4096;
#pragma unroll
    for (int i = 0; i < 4; ++i) {
        float4 o = make_float4(acc[i][0], acc[i][1], acc[i][2], acc[i][3]);
        kvp4[(base + (size_t)(dbase + i) * 64 + mbase) / 4] = o;
    }
    if ((t & 15) == 0) {
#pragma unroll
        for (int i = 0; i < 4; ++i)
            kspart[(size_t)(bh * S + s) * 64 + dbase + i] = ksum[i];
    }
}

// ---------------------------------------------------------------------------
// Kernel 1b: reduce partials -> KV, Ksum; M[d][j] = sum_m KV[d][m]*W[j][h*64+m]
// grid 64 blocks (bh), 256 threads. Tiny kernel.
// ---------------------------------------------------------------------------
__global__ __launch_bounds__(256) void k_makeM(const float* __restrict__ kvpart,
                                               const float* __restrict__ kspart,
                                               const float* __restrict__ W,
                                               float* __restrict__ M,
                                               float* __restrict__ Ksum,
                                               int S) {
    const int bh = blockIdx.x;
    const int h  = bh & 15;
    const int t  = threadIdx.x;

    __shared__ float KVs[64][68];
    __shared__ float Ws[64][68];    // Ws[j][m]

    const float4* kv4 = (const float4*)kvpart;
    const float4* W4  = (const float4*)W;

    for (int idx = t; idx < 1024; idx += 256) {
        int row = idx >> 4, c4 = idx & 15;
        float4 r = make_float4(0.f, 0.f, 0.f, 0.f);
        for (int s = 0; s < S; ++s) {
            float4 a = kv4[(size_t)(bh * S + s) * 1024 + idx];
            r.x += a.x; r.y += a.y; r.z += a.z; r.w += a.w;
        }
        *(float4*)&KVs[row][c4 * 4] = r;
        *(float4*)&Ws[row][c4 * 4] = W4[(size_t)row * 256 + h * 16 + c4];
    }
    if (t < 64) {
        float ks = 0.f;
        for (int s = 0; s < S; ++s) ks += kspart[(size_t)(bh * S + s) * 64 + t];
        Ksum[(size_t)bh * 64 + t] = ks;
    }
    __syncthreads();

    const int dbase = (t >> 4) * 4, jbase = (t & 15) * 4;
    float acc[4][4] = {{0.f}};
#pragma unroll 4
    for (int m4 = 0; m4 < 16; ++m4) {
        float4 kvr[4], wr[4];
#pragma unroll
        for (int i = 0; i < 4; ++i) kvr[i] = *(const float4*)&KVs[dbase + i][m4 * 4];
#pragma unroll
        for (int j = 0; j < 4; ++j) wr[j] = *(const float4*)&Ws[jbase + j][m4 * 4];
#pragma unroll
        for (int i = 0; i < 4; ++i)
#pragma unroll
            for (int j = 0; j < 4; ++j)
                acc[i][j] += kvr[i].x * wr[j].x + kvr[i].y * wr[j].y +
                             kvr[i].z * wr[j].z + kvr[i].w * wr[j].w;
    }
    float4* M4 = (float4*)M;
#pragma unroll
    for (int i = 0; i < 4; ++i)
        M4[((size_t)bh * 4096 + (size_t)(dbase + i) * 64 + jbase) / 4] =
            make_float4(acc[i][0], acc[i][1], acc[i][2], acc[i][3]);
}

// ---------------------------------------------------------------------------
// Kernel 2: partial_out[hs][b,n,j] = sum_{h in slice} z_h(n) * phiQ_h[n,:] . M_h[:,j]
// grid (64 n-chunks, 4 b, HS h-slices), 256 threads; 64 rows of n per block.
// ---------------------------------------------------------------------------
__global__ __launch_bounds__(256) void k_out(const float* __restrict__ Q,
                                             const float* __restrict__ M,
                                             const float* __restrict__ Ksum,
                                             float* __restrict__ outpart) {
    const int nc = blockIdx.x;     // 0..63
    const int b  = blockIdx.y;     // 0..3
    const int hs = blockIdx.z;     // 0..HS-1
    const int HS = gridDim.z;
    const int hper = H_ / HS;
    const int n0 = nc * 64;
    const int t  = threadIdx.x;

    __shared__ float Ms[64][68];    // Ms[d][j]     (pad 68: 2-way only)
    __shared__ float QsT[64][65];   // QsT[d][i]    (pad 65: kills 8-way write conflict)
    __shared__ float zp[4][64];     // quarter-partials of Q.Ksum per row
    __shared__ float Kss[64];

    const int ibase = (t >> 4) * 4, jbase = (t & 15) * 4;
    const int qtr = t >> 6, zrow = t & 63;
    float acc[4][4] = {{0.f}};

    const float4* Qf4 = (const float4*)Q;
    const float4* Mf4 = (const float4*)M;

    for (int hh = 0; hh < hper; ++hh) {
        const int h  = hs * hper + hh;
        const int bh = b * 16 + h;
        __syncthreads();   // protect LDS from previous iteration
#pragma unroll
        for (int rep = 0; rep < 4; ++rep) {
            int idx = t + rep * 256;
            int row = idx >> 4, c4 = idx & 15;
            *(float4*)&Ms[row][c4 * 4] = Mf4[(size_t)bh * 1024 + idx];
            float4 qq = Qf4[(size_t)(b * N_ + n0 + row) * 256 + h * 16 + c4];
            QsT[c4 * 4 + 0][row] = phi(qq.x);
            QsT[c4 * 4 + 1][row] = phi(qq.y);
            QsT[c4 * 4 + 2][row] = phi(qq.z);
            QsT[c4 * 4 + 3][row] = phi(qq.w);
        }
        if (t < 64) Kss[t] = Ksum[(size_t)bh * 64 + t];
        __syncthreads();

        // z partials: all 256 threads, 16 d's each
        {
            float part = 0.f;
#pragma unroll
            for (int dd = 0; dd < 16; ++dd) {
                int d = qtr * 16 + dd;
                part += QsT[d][zrow] * Kss[d];
            }
            zp[qtr][zrow] = part;
        }
        __syncthreads();

        float sacc[4][4] = {{0.f}};
#pragma unroll 8
        for (int d = 0; d < 64; ++d) {
            float4 qi = *(const float4*)&QsT[d][ibase];
            float4 mj = *(const float4*)&Ms[d][jbase];
            float qa[4] = {qi.x, qi.y, qi.z, qi.w};
            float ma[4] = {mj.x, mj.y, mj.z, mj.w};
#pragma unroll
            for (int i = 0; i < 4; ++i)
#pragma unroll
                for (int j = 0; j < 4; ++j) sacc[i][j] += qa[i] * ma[j];
        }
#pragma unroll
        for (int i = 0; i < 4; ++i) {
            int r = ibase + i;
            float z = 1.0f / (zp[0][r] + zp[1][r] + zp[2][r] + zp[3][r] + EPS_);
#pragma unroll
            for (int j = 0; j < 4; ++j) acc[i][j] += z * sacc[i][j];
        }
    }

    float4* O4 = (float4*)outpart;
    const size_t slice = (size_t)hs * (B_ * N_ * 64);
#pragma unroll
    for (int i = 0; i < 4; ++i) {
        float4 o = make_float4(acc[i][0], acc[i][1], acc[i][2], acc[i][3]);
        O4[(slice + (size_t)(b * N_ + n0 + ibase + i) * 64 + jbase) / 4] = o;
    }
}

// ---------------------------------------------------------------------------
// Kernel 3: out = bias + sum_hs outpart[hs]
// ---------------------------------------------------------------------------
__global__ __launch_bounds__(256) void k_red(const float* __restrict__ outpart,
                                             const float* __restrict__ bout,
                                             float* __restrict__ out, int HS) {
    const int p = blockIdx.x * 256 + threadIdx.x;   // float4 index, 0..262143
    const float4* P4 = (const float4*)outpart;
    const float4* B4 = (const float4*)bout;
    float4 o = B4[p & 15];
    const int stride = B_ * N_ * 64 / 4;
    for (int hs = 0; hs < HS; ++hs) {
        float4 a = P4[(size_t)hs * stride + p];
        o.x += a.x; o.y += a.y; o.z += a.z; o.w += a.w;
    }
    ((float4*)out)[p] = o;
}

// ---------------------------------------------------------------------------
extern "C" void kernel_launch(void* const* d_in, const int* in_sizes, int n_in,
                              void* d_out, int out_size, void* d_ws, size_t ws_size,
                              hipStream_t stream) {
    const float* q  = (const float*)d_in[0];
    const float* k  = (const float*)d_in[1];
    const float* v  = (const float*)d_in[2];
    const float* W  = (const float*)d_in[3];
    const float* bo = (const float*)d_in[4];
    float* out = (float*)d_out;

    // Choose split factors by available workspace.
    int S = 16, HS = 4;
    {
        size_t need = ((size_t)BH_ * 16 * 4096 + (size_t)BH_ * 16 * 64 +
                       (size_t)BH_ * 4096 + BH_ * 64 +
                       (size_t)4 * B_ * N_ * 64) * 4;
        if (ws_size < need) { S = 4; HS = 1; }
    }

    float* ws      = (float*)d_ws;
    float* kvpart  = ws;
    float* kspart  = kvpart + (size_t)BH_ * S * 4096;
    float* M       = kspart + (size_t)BH_ * S * 64;
    float* Ksum    = M + (size_t)BH_ * 4096;
    float* outpart = Ksum + (size_t)BH_ * 64;

    k_kvpart<<<dim3(BH_, S), 256, 0, stream>>>(k, v, kvpart, kspart);
    k_makeM<<<BH_, 256, 0, stream>>>(kvpart, kspart, W, M, Ksum, S);
    k_out<<<dim3(N_ / 64, B_, HS), 256, 0, stream>>>(q, M, Ksum, outpart);
    k_red<<<B_ * N_ * 64 / 4 / 256, 256, 0, stream>>>(outpart, bo, out, HS);
}

// Round 3
// 248.399 us; speedup vs baseline: 1.2238x; 1.0610x over previous
//
#include <hip/hip_runtime.h>

#define B_  4
#define N_  4096
#define H_  16
#define D_  64
#define BH_ 64
#define S_  8
#define HS_ 4
#define EPS_ 1e-6f

typedef _Float16 h2  __attribute__((ext_vector_type(2)));
typedef float    f4v __attribute__((ext_vector_type(4)));

struct H2x4 { h2 e[4]; };

__device__ __forceinline__ H2x4 ld_h2x4(const h2* p) {
    f4v r = *(const f4v*)p;                 // ds_read_b128
    return __builtin_bit_cast(H2x4, r);
}

__device__ __forceinline__ float phi(float x) {
    // elu(x)+1 : x>0 -> x+1 ; x<=0 -> exp(x)
    return x > 0.0f ? x + 1.0f : __expf(x);
}

__device__ __forceinline__ float fdot2(h2 a, h2 b, float c) {
    return __builtin_amdgcn_fdot2(a, b, c, false);
}

// ---------------------------------------------------------------------------
// Kernel 1a: partial KV[d][m] = sum_n phi(K[n,d]) * V[n,m], partial Ksum.
// grid (64 bh, 8 s), 256 threads (4 waves). Each wave owns 16 n-rows of each
// staged 64-row chunk with an 8x8 fp32 tile/lane (full 64x64 per wave);
// wave partials reduced through LDS at block end. LDS tiles are fp16
// n-pair-interleaved half2, contracted with v_dot2_f32_f16.
// ---------------------------------------------------------------------------
__global__ __launch_bounds__(256) void k_kvpart(const float* __restrict__ K,
                                                const float* __restrict__ V,
                                                float* __restrict__ kvpart,
                                                float* __restrict__ kspart) {
    const int bh = blockIdx.x;          // 0..63
    const int s  = blockIdx.y;          // 0..7
    const int b  = bh >> 4;
    const int h  = bh & 15;
    const int t  = threadIdx.x;
    const int w  = t >> 6;              // wave 0..3
    const int lane = t & 63;

    // pool: phase 1: Kp[32][68] h2 (8704 B) + Vp[32][68] h2 -> 17408 B
    //       phase 2: Red[2][64*68] fp32 -> 34816 B
    __shared__ __align__(16) float pool[2 * 64 * 68];
    __shared__ float ksred[4][64];

    h2* Kp = (h2*)pool;                  // [c][d] : {phiK[2c][d], phiK[2c+1][d]}
    h2* Vp = (h2*)(pool + 2176);         // Kp = 32*68 h2 = 2176 floats

    const int dbase = (lane >> 3) * 8;
    const int mbase = (lane & 7) * 8;

    float acc[8][8] = {{0.f}};
    float ksum[8]   = {0.f};
    h2 one2; one2.x = (_Float16)1.0f; one2.y = (_Float16)1.0f;

    const float4* Kf4 = (const float4*)K;
    const float4* Vf4 = (const float4*)V;

    for (int chunk = 0; chunk < (N_ / S_) / 64; ++chunk) {
        const int n0 = s * (N_ / S_) + chunk * 64;
        __syncthreads();
        // stage K then V: each iter a thread loads two rows (2rp, 2rp+1) of one
        // float4 d-group and writes 4 interleaved half2 as one b128.
#pragma unroll
        for (int rep = 0; rep < 2; ++rep) {
            int idx = t + rep * 256;            // 0..511
            int rp = idx >> 4, c4 = idx & 15;
            size_t g = (size_t)(b * N_ + n0 + 2 * rp) * 256 + h * 16 + c4;
            float4 a = Kf4[g];
            float4 c = Kf4[g + 256];
            H2x4 o;
            o.e[0].x = (_Float16)phi(a.x); o.e[0].y = (_Float16)phi(c.x);
            o.e[1].x = (_Float16)phi(a.y); o.e[1].y = (_Float16)phi(c.y);
            o.e[2].x = (_Float16)phi(a.z); o.e[2].y = (_Float16)phi(c.z);
            o.e[3].x = (_Float16)phi(a.w); o.e[3].y = (_Float16)phi(c.w);
            *(f4v*)&Kp[rp * 68 + c4 * 4] = __builtin_bit_cast(f4v, o);
        }
#pragma unroll
        for (int rep = 0; rep < 2; ++rep) {
            int idx = t + rep * 256;
            int rp = idx >> 4, c4 = idx & 15;
            size_t g = (size_t)(b * N_ + n0 + 2 * rp) * 256 + h * 16 + c4;
            float4 a = Vf4[g];
            float4 c = Vf4[g + 256];
            H2x4 o;
            o.e[0].x = (_Float16)a.x; o.e[0].y = (_Float16)c.x;
            o.e[1].x = (_Float16)a.y; o.e[1].y = (_Float16)c.y;
            o.e[2].x = (_Float16)a.z; o.e[2].y = (_Float16)c.z;
            o.e[3].x = (_Float16)a.w; o.e[3].y = (_Float16)c.w;
            *(f4v*)&Vp[rp * 68 + c4 * 4] = __builtin_bit_cast(f4v, o);
        }
        __syncthreads();
#pragma unroll
        for (int cc = 0; cc < 8; ++cc) {
            int c = w * 8 + cc;                 // n-pair index in chunk
            H2x4 kd0 = ld_h2x4(&Kp[c * 68 + dbase]);
            H2x4 kd1 = ld_h2x4(&Kp[c * 68 + dbase + 4]);
            H2x4 vm0 = ld_h2x4(&Vp[c * 68 + mbase]);
            H2x4 vm1 = ld_h2x4(&Vp[c * 68 + mbase + 4]);
            h2 kd[8] = {kd0.e[0], kd0.e[1], kd0.e[2], kd0.e[3],
                        kd1.e[0], kd1.e[1], kd1.e[2], kd1.e[3]};
            h2 vm[8] = {vm0.e[0], vm0.e[1], vm0.e[2], vm0.e[3],
                        vm1.e[0], vm1.e[1], vm1.e[2], vm1.e[3]};
#pragma unroll
            for (int i = 0; i < 8; ++i) {
#pragma unroll
                for (int j = 0; j < 8; ++j) acc[i][j] = fdot2(kd[i], vm[j], acc[i][j]);
                ksum[i] = fdot2(kd[i], one2, ksum[i]);
            }
        }
    }

    // ---- block-end reduction of 4 wave tiles ----
    if ((lane & 7) == 0) {
#pragma unroll
        for (int i = 0; i < 8; ++i) ksred[w][dbase + i] = ksum[i];
    }
    float* Red = pool;                   // [2][64*68]
    __syncthreads();

#define WRITE_T(slot)                                                          \
    {   float* T = Red + (slot) * 64 * 68;                                     \
        _Pragma("unroll")                                                      \
        for (int i = 0; i < 8; ++i) {                                          \
            f4v o0 = {acc[i][0], acc[i][1], acc[i][2], acc[i][3]};             \
            f4v o1 = {acc[i][4], acc[i][5], acc[i][6], acc[i][7]};             \
            *(f4v*)&T[(dbase + i) * 68 + mbase]     = o0;                      \
            *(f4v*)&T[(dbase + i) * 68 + mbase + 4] = o1;                      \
        } }
#define ADD_T(slot)                                                            \
    {   float* T = Red + (slot) * 64 * 68;                                     \
        _Pragma("unroll")                                                      \
        for (int i = 0; i < 8; ++i) {                                          \
            f4v r0 = *(f4v*)&T[(dbase + i) * 68 + mbase];                      \
            f4v r1 = *(f4v*)&T[(dbase + i) * 68 + mbase + 4];                  \
            acc[i][0] += r0[0]; acc[i][1] += r0[1];                            \
            acc[i][2] += r0[2]; acc[i][3] += r0[3];                            \
            acc[i][4] += r1[0]; acc[i][5] += r1[1];                            \
            acc[i][6] += r1[2]; acc[i][7] += r1[3];                            \
        } }

    if (w == 1) WRITE_T(0);
    if (w == 3) WRITE_T(1);
    __syncthreads();
    if (w == 0) ADD_T(0);
    if (w == 2) ADD_T(1);
    __syncthreads();
    if (w == 2) WRITE_T(0);
    __syncthreads();
    if (w == 0) {
        ADD_T(0);
        float4* kvp4 = (float4*)kvpart;
        const size_t base = (size_t)(bh * S_ + s) * 4096;
#pragma unroll
        for (int i = 0; i < 8; ++i) {
            float4 o0 = make_float4(acc[i][0], acc[i][1], acc[i][2], acc[i][3]);
            float4 o1 = make_float4(acc[i][4], acc[i][5], acc[i][6], acc[i][7]);
            kvp4[(base + (size_t)(dbase + i) * 64 + mbase) / 4]     = o0;
            kvp4[(base + (size_t)(dbase + i) * 64 + mbase + 4) / 4] = o1;
        }
        float ks = ksred[0][lane] + ksred[1][lane] + ksred[2][lane] + ksred[3][lane];
        kspart[(size_t)(bh * S_ + s) * 64 + lane] = ks;
    }
#undef WRITE_T
#undef ADD_T
}

// ---------------------------------------------------------------------------
// Kernel 1b: reduce partials -> KV, Ksum; M[d][j] = sum_m KV[d][m]*W[j][h*64+m]
// M stored d-pair-interleaved as half2 for the fdot2 consumer. grid 64, tiny.
// ---------------------------------------------------------------------------
__global__ __launch_bounds__(256) void k_makeM(const float* __restrict__ kvpart,
                                               const float* __restrict__ kspart,
                                               const float* __restrict__ W,
                                               float* __restrict__ Mh,
                                               float* __restrict__ Ksum) {
    const int bh = blockIdx.x;
    const int h  = bh & 15;
    const int t  = threadIdx.x;

    __shared__ float KVs[64][68];
    __shared__ float Ws[64][68];    // Ws[j][m]

    const float4* kv4 = (const float4*)kvpart;
    const float4* W4  = (const float4*)W;

    for (int idx = t; idx < 1024; idx += 256) {
        int row = idx >> 4, c4 = idx & 15;
        float4 r = make_float4(0.f, 0.f, 0.f, 0.f);
        for (int s = 0; s < S_; ++s) {
            float4 a = kv4[(size_t)(bh * S_ + s) * 1024 + idx];
            r.x += a.x; r.y += a.y; r.z += a.z; r.w += a.w;
        }
        *(float4*)&KVs[row][c4 * 4] = r;
        *(float4*)&Ws[row][c4 * 4] = W4[(size_t)row * 256 + h * 16 + c4];
    }
    if (t < 64) {
        float ks = 0.f;
        for (int s = 0; s < S_; ++s) ks += kspart[(size_t)(bh * S_ + s) * 64 + t];
        Ksum[(size_t)bh * 64 + t] = ks;
    }
    __syncthreads();

    const int dbase = (t >> 4) * 4, jbase = (t & 15) * 4;
    float acc[4][4] = {{0.f}};
#pragma unroll 4
    for (int m4 = 0; m4 < 16; ++m4) {
        float4 kvr[4], wr[4];
#pragma unroll
        for (int i = 0; i < 4; ++i) kvr[i] = *(const float4*)&KVs[dbase + i][m4 * 4];
#pragma unroll
        for (int j = 0; j < 4; ++j) wr[j] = *(const float4*)&Ws[jbase + j][m4 * 4];
#pragma unroll
        for (int i = 0; i < 4; ++i)
#pragma unroll
            for (int j = 0; j < 4; ++j)
                acc[i][j] += kvr[i].x * wr[j].x + kvr[i].y * wr[j].y +
                             kvr[i].z * wr[j].z + kvr[i].w * wr[j].w;
    }
    // Mh[bh][c][j] = half2{ M[2c][j], M[2c+1][j] },  c in [0,32), j in [0,64)
    f4v* M4 = (f4v*)Mh;
#pragma unroll
    for (int p = 0; p < 2; ++p) {
        int c = (dbase >> 1) + p;
        H2x4 o;
#pragma unroll
        for (int j = 0; j < 4; ++j) {
            o.e[j].x = (_Float16)acc[2 * p][j];
            o.e[j].y = (_Float16)acc[2 * p + 1][j];
        }
        M4[((size_t)bh * 2048 + c * 64 + jbase) / 4] = __builtin_bit_cast(f4v, o);
    }
}

// ---------------------------------------------------------------------------
// Kernel 2: outpart[hs][b,n,j] = sum_{h in slice} z_h(n) * phiQ_h[n,:] . M_h[:,j]
// grid (32 nc, 4 b, 4 hs), 256 threads; 128 n-rows per block, 8n x 4j per
// thread, z-dot folded into the main fdot2 contraction.
// ---------------------------------------------------------------------------
__global__ __launch_bounds__(256) void k_out(const float* __restrict__ Q,
                                             const float* __restrict__ Mh,
                                             const float* __restrict__ Ksum,
                                             float* __restrict__ outpart) {
    const int nc = blockIdx.x;     // 0..31
    const int b  = blockIdx.y;     // 0..3
    const int hs = blockIdx.z;     // 0..3
    const int n0 = nc * 128;
    const int t  = threadIdx.x;

    __shared__ __align__(16) h2 QpT[32][132];  // [c][n]: {phiQ[n][2c], phiQ[n][2c+1]}
    __shared__ __align__(16) h2 Msp[32][68];   // [c][j]: {M[2c][j], M[2c+1][j]}
    __shared__ h2 Kssh[32];

    const int ibase = (t >> 4) * 8;   // n-row group 0..120
    const int jbase = (t & 15) * 4;   // j group 0..60
    float acc_out[8][4] = {{0.f}};

    const float4* Qf4 = (const float4*)Q;
    const f4v*    M4  = (const f4v*)Mh;

    for (int hh = 0; hh < 4; ++hh) {
        const int h  = hs * 4 + hh;
        const int bh = b * 16 + h;
        __syncthreads();
        // stage Q (2048 float4 -> transposed d-pair half2)
#pragma unroll
        for (int rep = 0; rep < 8; ++rep) {
            int idx = t + rep * 256;            // 0..2047
            int row = idx >> 4, c4 = idx & 15;
            float4 qq = Qf4[(size_t)(b * N_ + n0 + row) * 256 + h * 16 + c4];
            h2 p0; p0.x = (_Float16)phi(qq.x); p0.y = (_Float16)phi(qq.y);
            h2 p1; p1.x = (_Float16)phi(qq.z); p1.y = (_Float16)phi(qq.w);
            QpT[2 * c4][row]     = p0;
            QpT[2 * c4 + 1][row] = p1;
        }
        // stage M (512 x b128)
#pragma unroll
        for (int rep = 0; rep < 2; ++rep) {
            int i2 = t + rep * 256;             // 0..511
            int c = i2 >> 4, j4 = (i2 & 15) * 4;
            *(f4v*)&Msp[c][j4] = M4[(size_t)bh * 512 + i2];
        }
        if (t < 32) {
            h2 ks; ks.x = (_Float16)Ksum[(size_t)bh * 64 + 2 * t];
            ks.y = (_Float16)Ksum[(size_t)bh * 64 + 2 * t + 1];
            Kssh[t] = ks;
        }
        __syncthreads();

        float sacc[8][4] = {{0.f}};
        float zacc[8]    = {0.f};
#pragma unroll 4
        for (int c = 0; c < 32; ++c) {
            H2x4 qa = ld_h2x4(&QpT[c][ibase]);
            H2x4 qb = ld_h2x4(&QpT[c][ibase + 4]);
            H2x4 mm = ld_h2x4(&Msp[c][jbase]);
            h2 ks = Kssh[c];
            h2 q[8] = {qa.e[0], qa.e[1], qa.e[2], qa.e[3],
                       qb.e[0], qb.e[1], qb.e[2], qb.e[3]};
#pragma unroll
            for (int i = 0; i < 8; ++i) {
                zacc[i] = fdot2(q[i], ks, zacc[i]);
#pragma unroll
                for (int j = 0; j < 4; ++j) sacc[i][j] = fdot2(q[i], mm.e[j], sacc[i][j]);
            }
        }
#pragma unroll
        for (int i = 0; i < 8; ++i) {
            float z = 1.0f / (zacc[i] + EPS_);
#pragma unroll
            for (int j = 0; j < 4; ++j) acc_out[i][j] += z * sacc[i][j];
        }
    }

    float4* O4 = (float4*)outpart;
    const size_t slice = (size_t)hs * (B_ * N_ * 64);
#pragma unroll
    for (int i = 0; i < 8; ++i) {
        float4 o = make_float4(acc_out[i][0], acc_out[i][1], acc_out[i][2], acc_out[i][3]);
        O4[(slice + (size_t)(b * N_ + n0 + ibase + i) * 64 + jbase) / 4] = o;
    }
}

// ---------------------------------------------------------------------------
// Kernel 3: out = bias + sum_hs outpart[hs]
// ---------------------------------------------------------------------------
__global__ __launch_bounds__(256) void k_red(const float* __restrict__ outpart,
                                             const float* __restrict__ bout,
                                             float* __restrict__ out) {
    const int p = blockIdx.x * 256 + threadIdx.x;   // float4 index
    const float4* P4 = (const float4*)outpart;
    const float4* B4 = (const float4*)bout;
    float4 o = B4[p & 15];
    const int stride = B_ * N_ * 64 / 4;
#pragma unroll
    for (int hs = 0; hs < HS_; ++hs) {
        float4 a = P4[(size_t)hs * stride + p];
        o.x += a.x; o.y += a.y; o.z += a.z; o.w += a.w;
    }
    ((float4*)out)[p] = o;
}

// ---------------------------------------------------------------------------
extern "C" void kernel_launch(void* const* d_in, const int* in_sizes, int n_in,
                              void* d_out, int out_size, void* d_ws, size_t ws_size,
                              hipStream_t stream) {
    const float* q  = (const float*)d_in[0];
    const float* k  = (const float*)d_in[1];
    const float* v  = (const float*)d_in[2];
    const float* W  = (const float*)d_in[3];
    const float* bo = (const float*)d_in[4];
    float* out = (float*)d_out;

    float* ws      = (float*)d_ws;
    float* kvpart  = ws;                                    // 64*8*4096   = 2,097,152 f
    float* kspart  = kvpart + (size_t)BH_ * S_ * 4096;      // 64*8*64     = 32,768 f
    float* Mh      = kspart + (size_t)BH_ * S_ * 64;        // 64*2048 h2  = 131,072 f
    float* Ksum    = Mh + (size_t)BH_ * 2048;               // 64*64       = 4,096 f
    float* outpart = Ksum + (size_t)BH_ * 64;               // 4*1,048,576 f

    k_kvpart<<<dim3(BH_, S_), 256, 0, stream>>>(k, v, kvpart, kspart);
    k_makeM<<<BH_, 256, 0, stream>>>(kvpart, kspart, W, Mh, Ksum);
    k_out<<<dim3(N_ / 128, B_, HS_), 256, 0, stream>>>(q, Mh, Ksum, outpart);
    k_red<<<B_ * N_ * 64 / 4 / 256, 256, 0, stream>>>(outpart, bo, out);
}